// Round 4
// baseline (404.839 us; speedup 1.0000x reference)
//
#include <hip/hip_runtime.h>

typedef __attribute__((ext_vector_type(8))) short bf16x8;
typedef __attribute__((ext_vector_type(8))) unsigned short u16x8;
typedef __attribute__((ext_vector_type(4))) float f32x4;

#define MFMA16(a, b, c) __builtin_amdgcn_mfma_f32_16x16x32_bf16((a), (b), (c), 0, 0, 0)

__device__ __forceinline__ unsigned short f2bf(float f) {
  union { float f; unsigned u; } x; x.f = f;
  unsigned r = x.u + 0x7FFFu + ((x.u >> 16) & 1u);
  return (unsigned short)(r >> 16);
}
__device__ __forceinline__ float bf2f(unsigned short b) {
  union { unsigned u; float f; } x; x.u = ((unsigned)b) << 16;
  return x.f;
}

__device__ __forceinline__ void gld_lds16(const void* g, void* l) {
  __builtin_amdgcn_global_load_lds(
      (const __attribute__((address_space(1))) unsigned int*)g,
      (__attribute__((address_space(3))) unsigned int*)l, 16, 0, 0);
}

// ---------------- fp32 -> bf16 bulk convert (memory-bound) ------------------
__global__ __launch_bounds__(256) void cvt_kernel(const float* __restrict__ s,
                                                  unsigned short* __restrict__ d,
                                                  int n8) {
  int i = blockIdx.x * 256 + threadIdx.x;
  const int stride = gridDim.x * 256;
  for (; i < n8; i += stride) {
    float4 f0 = ((const float4*)s)[2 * i];
    float4 f1 = ((const float4*)s)[2 * i + 1];
    u16x8 v;
    v[0] = f2bf(f0.x); v[1] = f2bf(f0.y); v[2] = f2bf(f0.z); v[3] = f2bf(f0.w);
    v[4] = f2bf(f1.x); v[5] = f2bf(f1.y); v[6] = f2bf(f1.z); v[7] = f2bf(f1.w);
    ((u16x8*)d)[i] = v;
  }
}

// ======== 256x256 tile, BK=32, QUAD-buffer LDS, depth-3 counted vmcnt =======
// K = 768 -> 24 K-tiles of 32. Iter t: barrier (protects buf[(t-1)&3] readers)
// -> issue stage(t+3) -> s_waitcnt vmcnt(12) (waits ONLY stage(t); stages
// t+1..t+3 = 12 insts stay in flight ACROSS the barrier) -> s_barrier ->
// 12 ds_read_b128 + 32 MFMA.  No vmcnt(0) in the main loop (T4).
// Swizzle: chunk ^= row&3 (pre-swizzled global src, linear gld_lds dest).

#define BAR_A()                                             \
  {                                                         \
    __builtin_amdgcn_sched_barrier(0);                      \
    asm volatile("s_barrier" ::: "memory");                 \
    __builtin_amdgcn_sched_barrier(0);                      \
  }
#define WAIT12_BAR()                                                  \
  {                                                                   \
    __builtin_amdgcn_sched_barrier(0);                                \
    asm volatile("s_waitcnt vmcnt(12)\n\ts_barrier" ::: "memory");    \
    __builtin_amdgcn_sched_barrier(0);                                \
  }
#define WAIT0_BAR()                                                   \
  {                                                                   \
    __builtin_amdgcn_sched_barrier(0);                                \
    asm volatile("s_waitcnt vmcnt(0)\n\ts_barrier" ::: "memory");     \
    __builtin_amdgcn_sched_barrier(0);                                \
  }

// stage K-tile t into buffer q: A rows m0..m0+255, B rows n0..n0+255, cols
// [t*32, t*32+32).  Per wave: 2 insts A + 2 insts B, each 1KB (16 rows).
#define STAGE24(t, q)                                                 \
  {                                                                   \
    const unsigned short* pa = gA + (size_t)(t) * 32;                 \
    const unsigned short* pb = gB + (size_t)(t) * 32;                 \
    unsigned short* la = &As[q][wave * 32][0];                        \
    unsigned short* lb = &Bs[q][wave * 32][0];                        \
    gld_lds16(pa, la);                                                \
    gld_lds16(pa + (size_t)16 * 768, la + 16 * 32);                   \
    gld_lds16(pb, lb);                                                \
    gld_lds16(pb + (size_t)16 * 768, lb + 16 * 32);                   \
  }

#define COMPUTE24(q)                                                         \
  {                                                                          \
    bf16x8 bfr[4];                                                           \
    _Pragma("unroll") for (int n = 0; n < 4; n++) {                          \
      const int rb = wc * 64 + n * 16 + lrow;                                \
      bfr[n] = *(const bf16x8*)(&Bs[q][rb][(lgrp ^ (rb & 3)) << 3]);         \
    }                                                                        \
    _Pragma("unroll") for (int mf = 0; mf < 8; mf++) {                       \
      const int ra = wr * 128 + mf * 16 + lrow;                              \
      bf16x8 afr = *(const bf16x8*)(&As[q][ra][(lgrp ^ (ra & 3)) << 3]);     \
      __builtin_amdgcn_s_setprio(1);                                         \
      _Pragma("unroll") for (int n = 0; n < 4; n++)                          \
        acc[mf][n] = MFMA16(afr, bfr[n], acc[mf][n]);                        \
      __builtin_amdgcn_s_setprio(0);                                         \
    }                                                                        \
  }

#define GEMM_PREAMBLE(APTR, BPTR)                                            \
  const int tid = threadIdx.x;                                               \
  const int lane = tid & 63, wave = tid >> 6;                                \
  const int lrow = lane & 15, lgrp = lane >> 4;                              \
  const int wr = wave >> 2, wc = wave & 3;                                   \
  const int m0 = blockIdx.x * 256, n0 = blockIdx.y * 256;                    \
  f32x4 acc[8][4];                                                           \
  _Pragma("unroll") for (int i = 0; i < 8; i++)                              \
      _Pragma("unroll") for (int j = 0; j < 4; j++)                          \
          acc[i][j] = (f32x4){0.f, 0.f, 0.f, 0.f};                           \
  const int r0 = wave * 32 + (lane >> 2);                                    \
  const int cs = ((lane & 3) ^ (r0 & 3)) * 8;                                \
  const unsigned short* gA = (APTR) + (size_t)(m0 + r0) * 768 + cs;          \
  const unsigned short* gB = (BPTR) + (size_t)(n0 + r0) * 768 + cs;          \
  STAGE24(0, 0);                                                             \
  STAGE24(1, 1);                                                             \
  STAGE24(2, 2);                                                             \
  for (int t = 0; t < 24; ++t) {                                             \
    const int q = t & 3;                                                     \
    BAR_A();                                                                 \
    if (t < 21) {                                                            \
      STAGE24(t + 3, (t + 3) & 3);                                           \
      WAIT12_BAR();                                                          \
    } else {                                                                 \
      WAIT0_BAR();                                                           \
    }                                                                        \
    COMPUTE24(q);                                                            \
  }

// ---------------- GEMM1: qkv = Xb @ Wb.T -> scatter Q/K/V [BH][N][D] bf16 ---
__global__ __launch_bounds__(512, 2) void qkv_gemm(const unsigned short* __restrict__ X,
                                                   const unsigned short* __restrict__ W,
                                                   unsigned short* __restrict__ Qo,
                                                   unsigned short* __restrict__ Ko,
                                                   unsigned short* __restrict__ Vo) {
  __shared__ unsigned short As[4][256][32];
  __shared__ unsigned short Bs[4][256][32];
  GEMM_PREAMBLE(X, W);

#pragma unroll
  for (int n = 0; n < 4; n++) {
    const int jb = n0 + wc * 64 + n * 16;
    const int s = jb / 768;
    const int hh = (jb - s * 768) >> 6;
    const int dd = (jb & 63) + lrow;
    unsigned short* dst = (s == 0) ? Qo : (s == 1) ? Ko : Vo;
#pragma unroll
    for (int mf = 0; mf < 8; mf++) {
#pragma unroll
      for (int r = 0; r < 4; r++) {
        const int m = m0 + wr * 128 + mf * 16 + lgrp * 4 + r;
        if (m < 25216) {
          const int bb = m / 197;
          const int nn = m - bb * 197;
          dst[(size_t)((bb * 12 + hh) * 197 + nn) * 64 + dd] = f2bf(acc[mf][n][r]);
        }
      }
    }
  }
}

// ---------------- GEMM3: out = Oa @ Pb.T + proj_b  (fp32 out) ---------------
__global__ __launch_bounds__(512, 2) void proj_gemm(const unsigned short* __restrict__ A,
                                                    const unsigned short* __restrict__ W,
                                                    const float* __restrict__ bias,
                                                    float* __restrict__ out) {
  __shared__ unsigned short As[4][256][32];
  __shared__ unsigned short Bs[4][256][32];
  GEMM_PREAMBLE(A, W);

#pragma unroll
  for (int n = 0; n < 4; n++) {
    const int j = n0 + wc * 64 + n * 16 + lrow;
    const float bj = bias[j];
#pragma unroll
    for (int mf = 0; mf < 8; mf++) {
#pragma unroll
      for (int r = 0; r < 4; r++) {
        const int m = m0 + wr * 128 + mf * 16 + lgrp * 4 + r;
        if (m < 25216) out[(size_t)m * 768 + j] = acc[mf][n][r] + bj;
      }
    }
  }
}

// ---------------- Attention: per (b,h) block; dist-attn with pi weighting ----
__global__ __launch_bounds__(256) void attn_kernel(const unsigned short* __restrict__ Q,
                                                   const unsigned short* __restrict__ K,
                                                   const unsigned short* __restrict__ V,
                                                   const float* __restrict__ piq,
                                                   const float* __restrict__ pik,
                                                   unsigned short* __restrict__ Oa) {
  __shared__ unsigned short Qs[208][64];
  __shared__ unsigned short Ks[208][64];
  __shared__ unsigned short Vt[64][232];
  __shared__ unsigned short Ps[4][16][232];
  __shared__ float q2s[208], k2s[208], piqs[208], piks_[208];

  const int tid = threadIdx.x;
  const int lane = tid & 63, wave = tid >> 6;
  const int lrow = lane & 15, lgrp = lane >> 4;
  const int bh = blockIdx.x;
  const int h = bh % 12;
  const int b = bh / 12;

  {
    uint4 z = {0u, 0u, 0u, 0u};
    for (int i = tid; i < 1664; i += 256) { ((uint4*)Qs)[i] = z; ((uint4*)Ks)[i] = z; }
    for (int i = tid; i < 1856; i += 256) { ((uint4*)Vt)[i] = z; ((uint4*)Ps)[i] = z; }
  }
  __syncthreads();

  if (tid < 208) {
    const int n = tid;
    const bool valid = n < 197;
    float q2 = 0.f, k2 = 0.f;
    if (valid) {
      const size_t base = ((size_t)bh * 197 + n) * 64;
#pragma unroll
      for (int c = 0; c < 8; c++) {
        u16x8 vq = *(const u16x8*)(Q + base + c * 8);
        u16x8 vk = *(const u16x8*)(K + base + c * 8);
#pragma unroll
        for (int e = 0; e < 8; e++) {
          float fq = bf2f((unsigned short)vq[e]); q2 += fq * fq;
          float fk = bf2f((unsigned short)vk[e]); k2 += fk * fk;
        }
        int cs = c ^ (n & 7);
        *(u16x8*)(&Qs[n][cs << 3]) = vq;
        *(u16x8*)(&Ks[n][cs << 3]) = vk;
      }
#pragma unroll
      for (int c = 0; c < 8; c++) {
        u16x8 vv = *(const u16x8*)(V + base + c * 8);
#pragma unroll
        for (int e = 0; e < 8; e++) Vt[c * 8 + e][n] = (unsigned short)vv[e];
      }
    }
    q2s[n] = valid ? q2 : 0.f;
    k2s[n] = valid ? k2 : 1e30f;
    piqs[n] = valid ? fminf(fabsf(piq[h * 197 + n]), 1.f) : 0.f;
    piks_[n] = valid ? fminf(fabsf(pik[h * 197 + n]), 1.f) : 0.f;
  }
  __syncthreads();

  for (int t = wave; t < 13; t += 4) {
    const int n0 = t * 16;
    bf16x8 aq[2];
    {
      const int rq = n0 + lrow;
      aq[0] = *(const bf16x8*)(&Qs[rq][((0 + lgrp) ^ (rq & 7)) << 3]);
      aq[1] = *(const bf16x8*)(&Qs[rq][((4 + lgrp) ^ (rq & 7)) << 3]);
    }
    float rs[4] = {0.f, 0.f, 0.f, 0.f};
    float q2r[4];
#pragma unroll
    for (int r = 0; r < 4; r++) q2r[r] = q2s[n0 + lgrp * 4 + r];

    for (int jt = 0; jt < 13; jt++) {
      f32x4 sacc = (f32x4){0.f, 0.f, 0.f, 0.f};
      const int rk = jt * 16 + lrow;
      bf16x8 bk0 = *(const bf16x8*)(&Ks[rk][((0 + lgrp) ^ (rk & 7)) << 3]);
      bf16x8 bk1 = *(const bf16x8*)(&Ks[rk][((4 + lgrp) ^ (rk & 7)) << 3]);
      sacc = MFMA16(aq[0], bk0, sacc);
      sacc = MFMA16(aq[1], bk1, sacc);
      const int j = jt * 16 + lrow;
      const float k2j = k2s[j];
      const float pikj = piks_[j];
#pragma unroll
      for (int r = 0; r < 4; r++) {
        float sq = q2r[r] + k2j - 2.f * sacc[r];
        sq = fmaxf(sq, 0.f);
        float p = __expf(-0.0625f * sq) * pikj;
        rs[r] += p;
        Ps[wave][lgrp * 4 + r][j] = f2bf(p);
      }
    }
#pragma unroll
    for (int r = 0; r < 4; r++) {
      float v = rs[r];
      v += __shfl_xor(v, 1);
      v += __shfl_xor(v, 2);
      v += __shfl_xor(v, 4);
      v += __shfl_xor(v, 8);
      rs[r] = v;
    }
    float scale[4];
#pragma unroll
    for (int r = 0; r < 4; r++) {
      float pq = piqs[n0 + lgrp * 4 + r];
      scale[r] = pq / (pq * rs[r] + 1e-6f);
    }
    f32x4 o[4];
#pragma unroll
    for (int dt = 0; dt < 4; dt++) o[dt] = (f32x4){0.f, 0.f, 0.f, 0.f};
#pragma unroll
    for (int ks = 0; ks < 7; ks++) {
      bf16x8 ap = *(const bf16x8*)(&Ps[wave][lrow][ks * 32 + lgrp * 8]);
#pragma unroll
      for (int dt = 0; dt < 4; dt++) {
        bf16x8 bv = *(const bf16x8*)(&Vt[dt * 16 + lrow][ks * 32 + lgrp * 8]);
        o[dt] = MFMA16(ap, bv, o[dt]);
      }
    }
#pragma unroll
    for (int r = 0; r < 4; r++) {
      const int n = n0 + lgrp * 4 + r;
      if (n < 197) {
        const size_t ob = ((size_t)(b * 197 + n)) * 768 + h * 64;
#pragma unroll
        for (int dt = 0; dt < 4; dt++) Oa[ob + dt * 16 + lrow] = f2bf(o[dt][r] * scale[r]);
      }
    }
  }
}

extern "C" void kernel_launch(void* const* d_in, const int* in_sizes, int n_in,
                              void* d_out, int out_size, void* d_ws, size_t ws_size,
                              hipStream_t stream) {
  const float* x = (const float*)d_in[0];
  const float* qkv_w = (const float*)d_in[1];
  const float* proj_w = (const float*)d_in[2];
  const float* proj_b = (const float*)d_in[3];
  const float* pi_q = (const float*)d_in[4];
  const float* pi_k = (const float*)d_in[5];
  float* out = (float*)d_out;

  unsigned short* ws = (unsigned short*)d_ws;
  const size_t S = (size_t)1536 * 197 * 64;  // 19,365,888 elems per tensor
  unsigned short* Q = ws;
  unsigned short* K = ws + S;
  unsigned short* V = ws + 2 * S;
  unsigned short* Xb = ws + 3 * S;   // aliased: Oa reuses this region after qkv
  unsigned short* Oa = Xb;
  unsigned short* Wb = ws + 4 * S;                 // 2304*768 bf16
  unsigned short* Pb = Wb + (size_t)2304 * 768;    // 768*768 bf16

  dim3 blk(256, 1, 1);
  dim3 blk512(512, 1, 1);
  cvt_kernel<<<dim3(2048, 1, 1), blk, 0, stream>>>(x, Xb, 2420736);
  cvt_kernel<<<dim3(864, 1, 1), blk, 0, stream>>>(qkv_w, Wb, 221184);
  cvt_kernel<<<dim3(288, 1, 1), blk, 0, stream>>>(proj_w, Pb, 73728);
  qkv_gemm<<<dim3(99, 9, 1), blk512, 0, stream>>>(Xb, Wb, Q, K, V);
  attn_kernel<<<dim3(1536, 1, 1), blk, 0, stream>>>(Q, K, V, pi_q, pi_k, Oa);
  proj_gemm<<<dim3(99, 3, 1), blk512, 0, stream>>>(Oa, Pb, proj_b, out);
}

// Round 5
// 330.845 us; speedup vs baseline: 1.2237x; 1.2237x over previous
//
#include <hip/hip_runtime.h>

typedef __attribute__((ext_vector_type(8))) short bf16x8;
typedef __attribute__((ext_vector_type(8))) unsigned short u16x8;
typedef __attribute__((ext_vector_type(4))) float f32x4;

#define MFMA16(a, b, c) __builtin_amdgcn_mfma_f32_16x16x32_bf16((a), (b), (c), 0, 0, 0)

__device__ __forceinline__ unsigned short f2bf(float f) {
  union { float f; unsigned u; } x; x.f = f;
  unsigned r = x.u + 0x7FFFu + ((x.u >> 16) & 1u);
  return (unsigned short)(r >> 16);
}
__device__ __forceinline__ float bf2f(unsigned short b) {
  union { unsigned u; float f; } x; x.u = ((unsigned)b) << 16;
  return x.f;
}

__device__ __forceinline__ void gld_lds16(const void* g, void* l) {
  __builtin_amdgcn_global_load_lds(
      (const __attribute__((address_space(1))) unsigned int*)g,
      (__attribute__((address_space(3))) unsigned int*)l, 16, 0, 0);
}

// ---------------- fp32 -> bf16 bulk convert (memory-bound) ------------------
__global__ __launch_bounds__(256) void cvt_kernel(const float* __restrict__ s,
                                                  unsigned short* __restrict__ d,
                                                  int n8) {
  int i = blockIdx.x * 256 + threadIdx.x;
  const int stride = gridDim.x * 256;
  for (; i < n8; i += stride) {
    float4 f0 = ((const float4*)s)[2 * i];
    float4 f1 = ((const float4*)s)[2 * i + 1];
    u16x8 v;
    v[0] = f2bf(f0.x); v[1] = f2bf(f0.y); v[2] = f2bf(f0.z); v[3] = f2bf(f0.w);
    v[4] = f2bf(f1.x); v[5] = f2bf(f1.y); v[6] = f2bf(f1.z); v[7] = f2bf(f1.w);
    ((u16x8*)d)[i] = v;
  }
}

// ======= GEMMs: proven R2 m97-structure (128x128, BK=64, gld_lds w16) =======

// ---------------- GEMM1: qkv = Xb @ Wb.T -> scatter to Q/K/V [BH][N][D] bf16
__global__ __launch_bounds__(256) void qkv_gemm(const unsigned short* __restrict__ X,
                                                const unsigned short* __restrict__ W,
                                                unsigned short* __restrict__ Qo,
                                                unsigned short* __restrict__ Ko,
                                                unsigned short* __restrict__ Vo) {
  __shared__ unsigned short As[128][64];
  __shared__ unsigned short Bs[128][64];
  const int tid = threadIdx.x;
  const int lane = tid & 63, wave = tid >> 6;
  const int lrow = lane & 15, lgrp = lane >> 4;
  const int wr = wave >> 1, wc = wave & 1;
  const int m0 = blockIdx.x * 128, n0 = blockIdx.y * 128;

  f32x4 acc[4][4];
#pragma unroll
  for (int i = 0; i < 4; i++)
#pragma unroll
    for (int j = 0; j < 4; j++) acc[i][j] = (f32x4){0.f, 0.f, 0.f, 0.f};

  const int rbase = wave * 32;
  const int srow = rbase + (lane >> 3);
  const int scol = (lane & 7) * 8;

  for (int k0 = 0; k0 < 768; k0 += 64) {
    const unsigned short* ga = X + (size_t)(m0 + srow) * 768 + k0 + scol;
    const unsigned short* gb = W + (size_t)(n0 + srow) * 768 + k0 + scol;
#pragma unroll
    for (int i = 0; i < 4; i++) {
      gld_lds16(ga + (size_t)i * 8 * 768, &As[rbase + i * 8][0]);
      gld_lds16(gb + (size_t)i * 8 * 768, &Bs[rbase + i * 8][0]);
    }
    __syncthreads();
#pragma unroll
    for (int kk = 0; kk < 2; kk++) {
      bf16x8 a[4], b[4];
#pragma unroll
      for (int f = 0; f < 4; f++) {
        a[f] = *(const bf16x8*)(&As[wr * 64 + f * 16 + lrow][kk * 32 + lgrp * 8]);
        b[f] = *(const bf16x8*)(&Bs[wc * 64 + f * 16 + lrow][kk * 32 + lgrp * 8]);
      }
#pragma unroll
      for (int i = 0; i < 4; i++)
#pragma unroll
        for (int j = 0; j < 4; j++) acc[i][j] = MFMA16(a[i], b[j], acc[i][j]);
    }
    __syncthreads();
  }

#pragma unroll
  for (int fj = 0; fj < 4; fj++) {
    const int jb = n0 + wc * 64 + fj * 16;
    const int s = jb / 768;
    const int hh = (jb % 768) >> 6;
    const int dd = (jb & 63) + lrow;
    unsigned short* dst = (s == 0) ? Qo : (s == 1) ? Ko : Vo;
#pragma unroll
    for (int fi = 0; fi < 4; fi++) {
#pragma unroll
      for (int r = 0; r < 4; r++) {
        int m = m0 + wr * 64 + fi * 16 + lgrp * 4 + r;
        int bb = m / 197;
        int nn = m - bb * 197;
        dst[(size_t)((bb * 12 + hh) * 197 + nn) * 64 + dd] = f2bf(acc[fi][fj][r]);
      }
    }
  }
}

// ---------------- GEMM3: out = Oa @ Pb.T + proj_b  (fp32 out) ---------------
__global__ __launch_bounds__(256) void proj_gemm(const unsigned short* __restrict__ A,
                                                 const unsigned short* __restrict__ W,
                                                 const float* __restrict__ bias,
                                                 float* __restrict__ out) {
  __shared__ unsigned short As[128][64];
  __shared__ unsigned short Bs[128][64];
  const int tid = threadIdx.x;
  const int lane = tid & 63, wave = tid >> 6;
  const int lrow = lane & 15, lgrp = lane >> 4;
  const int wr = wave >> 1, wc = wave & 1;
  const int m0 = blockIdx.x * 128, n0 = blockIdx.y * 128;

  f32x4 acc[4][4];
#pragma unroll
  for (int i = 0; i < 4; i++)
#pragma unroll
    for (int j = 0; j < 4; j++) acc[i][j] = (f32x4){0.f, 0.f, 0.f, 0.f};

  const int rbase = wave * 32;
  const int srow = rbase + (lane >> 3);
  const int scol = (lane & 7) * 8;

  for (int k0 = 0; k0 < 768; k0 += 64) {
    const unsigned short* ga = A + (size_t)(m0 + srow) * 768 + k0 + scol;
    const unsigned short* gb = W + (size_t)(n0 + srow) * 768 + k0 + scol;
#pragma unroll
    for (int i = 0; i < 4; i++) {
      gld_lds16(ga + (size_t)i * 8 * 768, &As[rbase + i * 8][0]);
      gld_lds16(gb + (size_t)i * 8 * 768, &Bs[rbase + i * 8][0]);
    }
    __syncthreads();
#pragma unroll
    for (int kk = 0; kk < 2; kk++) {
      bf16x8 a[4], b[4];
#pragma unroll
      for (int f = 0; f < 4; f++) {
        a[f] = *(const bf16x8*)(&As[wr * 64 + f * 16 + lrow][kk * 32 + lgrp * 8]);
        b[f] = *(const bf16x8*)(&Bs[wc * 64 + f * 16 + lrow][kk * 32 + lgrp * 8]);
      }
#pragma unroll
      for (int i = 0; i < 4; i++)
#pragma unroll
        for (int j = 0; j < 4; j++) acc[i][j] = MFMA16(a[i], b[j], acc[i][j]);
    }
    __syncthreads();
  }

#pragma unroll
  for (int fj = 0; fj < 4; fj++) {
    const int j = n0 + wc * 64 + fj * 16 + lrow;
    const float bj = bias[j];
#pragma unroll
    for (int fi = 0; fi < 4; fi++) {
#pragma unroll
      for (int r = 0; r < 4; r++) {
        int m = m0 + wr * 64 + fi * 16 + lgrp * 4 + r;
        out[(size_t)m * 768 + j] = acc[fi][fj][r] + bj;
      }
    }
  }
}

// ============== Attention v2: 8 waves, no Qs, parallel staging ==============
// Per (b,h) block. LDS ~120KB -> 1 block/CU, but 8 waves (2/SIMD) and
// critical path = ceil(13/8) = 2 t-tiles per wave (was 4).
__global__ __launch_bounds__(512) void attn_kernel(const unsigned short* __restrict__ Q,
                                                   const unsigned short* __restrict__ K,
                                                   const unsigned short* __restrict__ V,
                                                   const float* __restrict__ piq,
                                                   const float* __restrict__ pik,
                                                   unsigned short* __restrict__ Oa) {
  __shared__ unsigned short Ks[208][64];   // XOR-swizzled (chunk ^= row&7)
  __shared__ unsigned short Vt[64][232];   // V transposed: Vt[d][n]
  __shared__ unsigned short Ps[8][16][232];
  __shared__ float k2s[208], piqs[208], piks_[208];

  const int tid = threadIdx.x;
  const int lane = tid & 63, wave = tid >> 6;
  const int lrow = lane & 15, lgrp = lane >> 4;
  const int bh = blockIdx.x;
  const int h = bh % 12;
  const int b = bh / 12;
  const size_t kvbase = (size_t)bh * 197 * 64;

  // ---- cooperative staging ----
  // K: 197 rows x 8 chunks of 16B; conflict-free swizzled b128 writes.
  for (int c = tid; c < 1576; c += 512) {
    const int row = c >> 3, ch = c & 7;
    u16x8 vk = *(const u16x8*)(K + kvbase + (size_t)row * 64 + ch * 8);
    *(u16x8*)(&Ks[row][(ch ^ (row & 7)) << 3]) = vk;
  }
  // V transpose: lane d = tid&63, row = c>>6; coalesced 2B global reads.
  for (int c = tid; c < 12608; c += 512) {
    const int row = c >> 6, d = c & 63;
    Vt[d][row] = V[kvbase + (size_t)row * 64 + d];
  }
  // zero tails (never written again): Ks rows 197..207, Vt cols 197..231,
  // Ps cols 208..231.
  for (int i = tid; i < 704; i += 512) Ks[197 + (i >> 6)][i & 63] = 0;
  for (int i = tid; i < 64 * 35; i += 512) Vt[i / 35][197 + (i % 35)] = 0;
  for (int i = tid; i < 8 * 16 * 24; i += 512) {
    const int w = i / 384, rem = i - w * 384;
    Ps[w][rem / 24][208 + (rem % 24)] = 0;
  }
  __syncthreads();

  // ---- k2 / pi (parallel, from LDS) ----
  if (tid < 208) {
    const int n = tid;
    if (n < 197) {
      float k2 = 0.f;
#pragma unroll
      for (int c = 0; c < 8; c++) {
        u16x8 v = *(const u16x8*)(&Ks[n][(c ^ (n & 7)) << 3]);
#pragma unroll
        for (int e = 0; e < 8; e++) { float f = bf2f((unsigned short)v[e]); k2 += f * f; }
      }
      k2s[n] = k2;
      piqs[n] = fminf(fabsf(piq[h * 197 + n]), 1.f);
      piks_[n] = fminf(fabsf(pik[h * 197 + n]), 1.f);
    } else {
      k2s[n] = 1e30f; piqs[n] = 0.f; piks_[n] = 0.f;
    }
  }
  __syncthreads();

  for (int t = wave; t < 13; t += 8) {
    const int n0 = t * 16;
    // Q fragments straight from global (row clamped; rows >=197 discarded).
    const int rq = min(n0 + lrow, 196);
    const size_t qb = kvbase + (size_t)rq * 64 + lgrp * 8;
    const bf16x8 aq0 = *(const bf16x8*)(Q + qb);
    const bf16x8 aq1 = *(const bf16x8*)(Q + qb + 32);
    // q2 in-register: partial over this lane's 16 d, reduce across lgrp.
    float q2p = 0.f;
#pragma unroll
    for (int e = 0; e < 8; e++) {
      float f0 = bf2f((unsigned short)((u16x8)aq0)[e]); q2p += f0 * f0;
      float f1 = bf2f((unsigned short)((u16x8)aq1)[e]); q2p += f1 * f1;
    }
    q2p += __shfl_xor(q2p, 16);
    q2p += __shfl_xor(q2p, 32);
    float q2r[4];
#pragma unroll
    for (int r = 0; r < 4; r++) q2r[r] = __shfl(q2p, lgrp * 4 + r);

    float rs[4] = {0.f, 0.f, 0.f, 0.f};
    for (int jt = 0; jt < 13; jt++) {
      f32x4 sacc = (f32x4){0.f, 0.f, 0.f, 0.f};
      const int rk = jt * 16 + lrow;
      bf16x8 bk0 = *(const bf16x8*)(&Ks[rk][((0 + lgrp) ^ (rk & 7)) << 3]);
      bf16x8 bk1 = *(const bf16x8*)(&Ks[rk][((4 + lgrp) ^ (rk & 7)) << 3]);
      sacc = MFMA16(aq0, bk0, sacc);
      sacc = MFMA16(aq1, bk1, sacc);
      const int j = jt * 16 + lrow;
      const float k2j = k2s[j];
      const float pikj = piks_[j];
#pragma unroll
      for (int r = 0; r < 4; r++) {
        float sq = q2r[r] + k2j - 2.f * sacc[r];
        sq = fmaxf(sq, 0.f);
        float p = __expf(-0.0625f * sq) * pikj;
        rs[r] += p;
        Ps[wave][lgrp * 4 + r][j] = f2bf(p);
      }
    }
#pragma unroll
    for (int r = 0; r < 4; r++) {
      float v = rs[r];
      v += __shfl_xor(v, 1);
      v += __shfl_xor(v, 2);
      v += __shfl_xor(v, 4);
      v += __shfl_xor(v, 8);
      rs[r] = v;
    }
    float scale[4];
#pragma unroll
    for (int r = 0; r < 4; r++) {
      float pq = piqs[n0 + lgrp * 4 + r];
      scale[r] = pq / (pq * rs[r] + 1e-6f);
    }
    f32x4 o[4];
#pragma unroll
    for (int dt = 0; dt < 4; dt++) o[dt] = (f32x4){0.f, 0.f, 0.f, 0.f};
    __builtin_amdgcn_s_setprio(1);
#pragma unroll
    for (int ks = 0; ks < 7; ks++) {
      bf16x8 ap = *(const bf16x8*)(&Ps[wave][lrow][ks * 32 + lgrp * 8]);
#pragma unroll
      for (int dt = 0; dt < 4; dt++) {
        bf16x8 bv = *(const bf16x8*)(&Vt[dt * 16 + lrow][ks * 32 + lgrp * 8]);
        o[dt] = MFMA16(ap, bv, o[dt]);
      }
    }
    __builtin_amdgcn_s_setprio(0);
#pragma unroll
    for (int r = 0; r < 4; r++) {
      const int n = n0 + lgrp * 4 + r;
      if (n < 197) {
        const size_t ob = ((size_t)(b * 197 + n)) * 768 + h * 64;
#pragma unroll
        for (int dt = 0; dt < 4; dt++) Oa[ob + dt * 16 + lrow] = f2bf(o[dt][r] * scale[r]);
      }
    }
  }
}

extern "C" void kernel_launch(void* const* d_in, const int* in_sizes, int n_in,
                              void* d_out, int out_size, void* d_ws, size_t ws_size,
                              hipStream_t stream) {
  const float* x = (const float*)d_in[0];
  const float* qkv_w = (const float*)d_in[1];
  const float* proj_w = (const float*)d_in[2];
  const float* proj_b = (const float*)d_in[3];
  const float* pi_q = (const float*)d_in[4];
  const float* pi_k = (const float*)d_in[5];
  float* out = (float*)d_out;

  unsigned short* ws = (unsigned short*)d_ws;
  const size_t S = (size_t)1536 * 197 * 64;  // 19,365,888 elems per tensor
  unsigned short* Q = ws;
  unsigned short* K = ws + S;
  unsigned short* V = ws + 2 * S;
  unsigned short* Xb = ws + 3 * S;   // aliased: Oa reuses this region after qkv
  unsigned short* Oa = Xb;
  unsigned short* Wb = ws + 4 * S;                 // 2304*768 bf16
  unsigned short* Pb = Wb + (size_t)2304 * 768;    // 768*768 bf16

  dim3 blk(256, 1, 1);
  dim3 blk512(512, 1, 1);
  cvt_kernel<<<dim3(2048, 1, 1), blk, 0, stream>>>(x, Xb, 2420736);
  cvt_kernel<<<dim3(864, 1, 1), blk, 0, stream>>>(qkv_w, Wb, 221184);
  cvt_kernel<<<dim3(288, 1, 1), blk, 0, stream>>>(proj_w, Pb, 73728);
  qkv_gemm<<<dim3(197, 18, 1), blk, 0, stream>>>(Xb, Wb, Q, K, V);
  attn_kernel<<<dim3(1536, 1, 1), blk512, 0, stream>>>(Q, K, V, pi_q, pi_k, Oa);
  proj_gemm<<<dim3(197, 6, 1), blk, 0, stream>>>(Oa, Pb, proj_b, out);
}

// Round 6
// 316.005 us; speedup vs baseline: 1.2811x; 1.0470x over previous
//
#include <hip/hip_runtime.h>

typedef __attribute__((ext_vector_type(8))) short bf16x8;
typedef __attribute__((ext_vector_type(8))) unsigned short u16x8;
typedef __attribute__((ext_vector_type(4))) float f32x4;

#define MFMA16(a, b, c) __builtin_amdgcn_mfma_f32_16x16x32_bf16((a), (b), (c), 0, 0, 0)

__device__ __forceinline__ unsigned short f2bf(float f) {
  union { float f; unsigned u; } x; x.f = f;
  unsigned r = x.u + 0x7FFFu + ((x.u >> 16) & 1u);
  return (unsigned short)(r >> 16);
}
__device__ __forceinline__ float bf2f(unsigned short b) {
  union { unsigned u; float f; } x; x.u = ((unsigned)b) << 16;
  return x.f;
}

__device__ __forceinline__ void gld_lds16(const void* g, void* l) {
  __builtin_amdgcn_global_load_lds(
      (const __attribute__((address_space(1))) unsigned int*)g,
      (__attribute__((address_space(3))) unsigned int*)l, 16, 0, 0);
}

// -------- fused fp32 -> bf16 bulk convert for x, qkv_w, proj_w --------------
__global__ __launch_bounds__(256) void cvt3_kernel(const float* __restrict__ s0,
                                                   unsigned short* __restrict__ d0, int n0,
                                                   const float* __restrict__ s1,
                                                   unsigned short* __restrict__ d1, int n1,
                                                   const float* __restrict__ s2,
                                                   unsigned short* __restrict__ d2, int n2) {
  int i = blockIdx.x * 256 + threadIdx.x;
  const int stride = gridDim.x * 256;
  const int tot = n0 + n1 + n2;
  for (; i < tot; i += stride) {
    const float* s;
    unsigned short* d;
    int j = i;
    if (j < n0) { s = s0; d = d0; }
    else if (j < n0 + n1) { j -= n0; s = s1; d = d1; }
    else { j -= n0 + n1; s = s2; d = d2; }
    float4 f0 = ((const float4*)s)[2 * j];
    float4 f1 = ((const float4*)s)[2 * j + 1];
    u16x8 v;
    v[0] = f2bf(f0.x); v[1] = f2bf(f0.y); v[2] = f2bf(f0.z); v[3] = f2bf(f0.w);
    v[4] = f2bf(f1.x); v[5] = f2bf(f1.y); v[6] = f2bf(f1.z); v[7] = f2bf(f1.w);
    ((u16x8*)d)[j] = v;
  }
}

// ======= GEMMs: proven R2 m97-structure (128x128, BK=64, gld_lds w16) =======

// ---------------- GEMM1: qkv = Xb @ Wb.T -> scatter to Q/K/V [BH][N][D] bf16
__global__ __launch_bounds__(256) void qkv_gemm(const unsigned short* __restrict__ X,
                                                const unsigned short* __restrict__ W,
                                                unsigned short* __restrict__ Qo,
                                                unsigned short* __restrict__ Ko,
                                                unsigned short* __restrict__ Vo) {
  __shared__ unsigned short As[128][64];
  __shared__ unsigned short Bs[128][64];
  const int tid = threadIdx.x;
  const int lane = tid & 63, wave = tid >> 6;
  const int lrow = lane & 15, lgrp = lane >> 4;
  const int wr = wave >> 1, wc = wave & 1;
  const int m0 = blockIdx.x * 128, n0 = blockIdx.y * 128;

  f32x4 acc[4][4];
#pragma unroll
  for (int i = 0; i < 4; i++)
#pragma unroll
    for (int j = 0; j < 4; j++) acc[i][j] = (f32x4){0.f, 0.f, 0.f, 0.f};

  const int rbase = wave * 32;
  const int srow = rbase + (lane >> 3);
  const int scol = (lane & 7) * 8;

  for (int k0 = 0; k0 < 768; k0 += 64) {
    const unsigned short* ga = X + (size_t)(m0 + srow) * 768 + k0 + scol;
    const unsigned short* gb = W + (size_t)(n0 + srow) * 768 + k0 + scol;
#pragma unroll
    for (int i = 0; i < 4; i++) {
      gld_lds16(ga + (size_t)i * 8 * 768, &As[rbase + i * 8][0]);
      gld_lds16(gb + (size_t)i * 8 * 768, &Bs[rbase + i * 8][0]);
    }
    __syncthreads();
#pragma unroll
    for (int kk = 0; kk < 2; kk++) {
      bf16x8 a[4], b[4];
#pragma unroll
      for (int f = 0; f < 4; f++) {
        a[f] = *(const bf16x8*)(&As[wr * 64 + f * 16 + lrow][kk * 32 + lgrp * 8]);
        b[f] = *(const bf16x8*)(&Bs[wc * 64 + f * 16 + lrow][kk * 32 + lgrp * 8]);
      }
#pragma unroll
      for (int i = 0; i < 4; i++)
#pragma unroll
        for (int j = 0; j < 4; j++) acc[i][j] = MFMA16(a[i], b[j], acc[i][j]);
    }
    __syncthreads();
  }

#pragma unroll
  for (int fj = 0; fj < 4; fj++) {
    const int jb = n0 + wc * 64 + fj * 16;
    const int s = jb / 768;
    const int hh = (jb % 768) >> 6;
    const int dd = (jb & 63) + lrow;
    unsigned short* dst = (s == 0) ? Qo : (s == 1) ? Ko : Vo;
#pragma unroll
    for (int fi = 0; fi < 4; fi++) {
#pragma unroll
      for (int r = 0; r < 4; r++) {
        int m = m0 + wr * 64 + fi * 16 + lgrp * 4 + r;
        int bb = m / 197;
        int nn = m - bb * 197;
        dst[(size_t)((bb * 12 + hh) * 197 + nn) * 64 + dd] = f2bf(acc[fi][fj][r]);
      }
    }
  }
}

// ---------------- GEMM3: out = Oa @ Pb.T + proj_b  (fp32 out) ---------------
__global__ __launch_bounds__(256) void proj_gemm(const unsigned short* __restrict__ A,
                                                 const unsigned short* __restrict__ W,
                                                 const float* __restrict__ bias,
                                                 float* __restrict__ out) {
  __shared__ unsigned short As[128][64];
  __shared__ unsigned short Bs[128][64];
  const int tid = threadIdx.x;
  const int lane = tid & 63, wave = tid >> 6;
  const int lrow = lane & 15, lgrp = lane >> 4;
  const int wr = wave >> 1, wc = wave & 1;
  const int m0 = blockIdx.x * 128, n0 = blockIdx.y * 128;

  f32x4 acc[4][4];
#pragma unroll
  for (int i = 0; i < 4; i++)
#pragma unroll
    for (int j = 0; j < 4; j++) acc[i][j] = (f32x4){0.f, 0.f, 0.f, 0.f};

  const int rbase = wave * 32;
  const int srow = rbase + (lane >> 3);
  const int scol = (lane & 7) * 8;

  for (int k0 = 0; k0 < 768; k0 += 64) {
    const unsigned short* ga = A + (size_t)(m0 + srow) * 768 + k0 + scol;
    const unsigned short* gb = W + (size_t)(n0 + srow) * 768 + k0 + scol;
#pragma unroll
    for (int i = 0; i < 4; i++) {
      gld_lds16(ga + (size_t)i * 8 * 768, &As[rbase + i * 8][0]);
      gld_lds16(gb + (size_t)i * 8 * 768, &Bs[rbase + i * 8][0]);
    }
    __syncthreads();
#pragma unroll
    for (int kk = 0; kk < 2; kk++) {
      bf16x8 a[4], b[4];
#pragma unroll
      for (int f = 0; f < 4; f++) {
        a[f] = *(const bf16x8*)(&As[wr * 64 + f * 16 + lrow][kk * 32 + lgrp * 8]);
        b[f] = *(const bf16x8*)(&Bs[wc * 64 + f * 16 + lrow][kk * 32 + lgrp * 8]);
      }
#pragma unroll
      for (int i = 0; i < 4; i++)
#pragma unroll
        for (int j = 0; j < 4; j++) acc[i][j] = MFMA16(a[i], b[j], acc[i][j]);
    }
    __syncthreads();
  }

#pragma unroll
  for (int fj = 0; fj < 4; fj++) {
    const int j = n0 + wc * 64 + fj * 16 + lrow;
    const float bj = bias[j];
#pragma unroll
    for (int fi = 0; fi < 4; fi++) {
#pragma unroll
      for (int r = 0; r < 4; r++) {
        int m = m0 + wr * 64 + fi * 16 + lgrp * 4 + r;
        out[(size_t)m * 768 + j] = acc[fi][fj][r] + bj;
      }
    }
  }
}

// ========= Attention v3: gld_lds staging + LDS->LDS swizzle/transpose =======
// Per (b,h) block, 8 waves. Staging: K,V -> linear LDS via global_load_lds
// (no VGPR round-trip, no per-element latency), then LDS->LDS builds of
// swizzled Ks and transposed Vt. Linear buffers alias Ps (dead until after
// the staging barrier).
__global__ __launch_bounds__(512) void attn_kernel(const unsigned short* __restrict__ Q,
                                                   const unsigned short* __restrict__ K,
                                                   const unsigned short* __restrict__ V,
                                                   const float* __restrict__ piq,
                                                   const float* __restrict__ pik,
                                                   unsigned short* __restrict__ Oa) {
  __shared__ unsigned short Ks[208][64];   // XOR-swizzled (chunk ^= row&7)
  __shared__ unsigned short Vt[64][232];   // V transposed: Vt[d][n]
  __shared__ unsigned short Ps[8][16][232];  // per-wave P; aliased during staging
  __shared__ float k2s[208], piqs[208], piks_[208];

  const int tid = threadIdx.x;
  const int lane = tid & 63, wave = tid >> 6;
  const int lrow = lane & 15, lgrp = lane >> 4;
  const int bh = blockIdx.x;
  const int h = bh % 12;
  const int b = bh / 12;
  const size_t kvbase = (size_t)bh * 197 * 64;

  unsigned short* Klin = &Ps[0][0][0];      // [208][64] linear, 13312 elems
  unsigned short* Vlin = Klin + 13312;      // [208][64] linear

  // ---- phase A: async-stage K,V linear (rows 197..207 = finite ws garbage)
  {
    const int rl = lane >> 3;
    const int cl = (lane & 7) * 8;
    for (int i = wave; i < 26; i += 8) {
      gld_lds16(K + kvbase + (size_t)(i * 8 + rl) * 64 + cl, Klin + i * 512);
      gld_lds16(V + kvbase + (size_t)(i * 8 + rl) * 64 + cl, Vlin + i * 512);
    }
  }
  __syncthreads();

  // ---- phase B: LDS->LDS builds + k2/pi (all-parallel, no global latency)
  for (int c = tid; c < 1664; c += 512) {
    const int row = c >> 3, ch = c & 7;
    u16x8 v = *(const u16x8*)(Klin + row * 64 + ch * 8);
    *(u16x8*)(&Ks[row][(ch ^ (row & 7)) << 3]) = v;
  }
  for (int c = tid; c < 1664; c += 512) {
    const int row = c >> 3, d0 = (c & 7) * 8;
    u16x8 v = *(const u16x8*)(Vlin + row * 64 + d0);
#pragma unroll
    for (int e = 0; e < 8; e++) Vt[d0 + e][row] = (unsigned short)v[e];
  }
  // Vt cols 208..231 are never staged: zero them (they meet Ps tail zeros,
  // and 0 * NaN-garbage would poison the PV MFMA).
  for (int i = tid; i < 1536; i += 512) Vt[i / 24][208 + (i % 24)] = 0;
  if (tid < 208) {
    const int n = tid;
    if (n < 197) {
      float k2 = 0.f;
#pragma unroll
      for (int c = 0; c < 8; c++) {
        u16x8 v = *(const u16x8*)(Klin + n * 64 + c * 8);
#pragma unroll
        for (int e = 0; e < 8; e++) { float f = bf2f((unsigned short)v[e]); k2 += f * f; }
      }
      k2s[n] = k2;
      piqs[n] = fminf(fabsf(piq[h * 197 + n]), 1.f);
      piks_[n] = fminf(fabsf(pik[h * 197 + n]), 1.f);
    } else {
      k2s[n] = 1e30f; piqs[n] = 0.f; piks_[n] = 0.f;
    }
  }
  __syncthreads();

  // per-wave Ps tail zero (cols 208..231); wave-local, no barrier needed.
  for (int i = lane; i < 384; i += 64) Ps[wave][i / 24][208 + (i % 24)] = 0;

  for (int t = wave; t < 13; t += 8) {
    const int n0 = t * 16;
    const int rq = min(n0 + lrow, 196);
    const size_t qb = kvbase + (size_t)rq * 64 + lgrp * 8;
    const bf16x8 aq0 = *(const bf16x8*)(Q + qb);
    const bf16x8 aq1 = *(const bf16x8*)(Q + qb + 32);
    float q2p = 0.f;
#pragma unroll
    for (int e = 0; e < 8; e++) {
      float f0 = bf2f((unsigned short)((u16x8)aq0)[e]); q2p += f0 * f0;
      float f1 = bf2f((unsigned short)((u16x8)aq1)[e]); q2p += f1 * f1;
    }
    q2p += __shfl_xor(q2p, 16);
    q2p += __shfl_xor(q2p, 32);
    float q2r[4];
#pragma unroll
    for (int r = 0; r < 4; r++) q2r[r] = __shfl(q2p, lgrp * 4 + r);

    float rs[4] = {0.f, 0.f, 0.f, 0.f};
    for (int jt = 0; jt < 13; jt++) {
      f32x4 sacc = (f32x4){0.f, 0.f, 0.f, 0.f};
      const int rk = jt * 16 + lrow;
      bf16x8 bk0 = *(const bf16x8*)(&Ks[rk][((0 + lgrp) ^ (rk & 7)) << 3]);
      bf16x8 bk1 = *(const bf16x8*)(&Ks[rk][((4 + lgrp) ^ (rk & 7)) << 3]);
      sacc = MFMA16(aq0, bk0, sacc);
      sacc = MFMA16(aq1, bk1, sacc);
      const int j = jt * 16 + lrow;
      const float k2j = k2s[j];
      const float pikj = piks_[j];
#pragma unroll
      for (int r = 0; r < 4; r++) {
        float sq = q2r[r] + k2j - 2.f * sacc[r];
        sq = fmaxf(sq, 0.f);
        float p = __expf(-0.0625f * sq) * pikj;
        rs[r] += p;
        Ps[wave][lgrp * 4 + r][j] = f2bf(p);
      }
    }
#pragma unroll
    for (int r = 0; r < 4; r++) {
      float v = rs[r];
      v += __shfl_xor(v, 1);
      v += __shfl_xor(v, 2);
      v += __shfl_xor(v, 4);
      v += __shfl_xor(v, 8);
      rs[r] = v;
    }
    float scale[4];
#pragma unroll
    for (int r = 0; r < 4; r++) {
      float pq = piqs[n0 + lgrp * 4 + r];
      scale[r] = pq / (pq * rs[r] + 1e-6f);
    }
    f32x4 o[4];
#pragma unroll
    for (int dt = 0; dt < 4; dt++) o[dt] = (f32x4){0.f, 0.f, 0.f, 0.f};
    __builtin_amdgcn_s_setprio(1);
#pragma unroll
    for (int ks = 0; ks < 7; ks++) {
      bf16x8 ap = *(const bf16x8*)(&Ps[wave][lrow][ks * 32 + lgrp * 8]);
#pragma unroll
      for (int dt = 0; dt < 4; dt++) {
        bf16x8 bv = *(const bf16x8*)(&Vt[dt * 16 + lrow][ks * 32 + lgrp * 8]);
        o[dt] = MFMA16(ap, bv, o[dt]);
      }
    }
    __builtin_amdgcn_s_setprio(0);
#pragma unroll
    for (int r = 0; r < 4; r++) {
      const int n = n0 + lgrp * 4 + r;
      if (n < 197) {
        const size_t ob = ((size_t)(b * 197 + n)) * 768 + h * 64;
#pragma unroll
        for (int dt = 0; dt < 4; dt++) Oa[ob + dt * 16 + lrow] = f2bf(o[dt][r] * scale[r]);
      }
    }
  }
}

extern "C" void kernel_launch(void* const* d_in, const int* in_sizes, int n_in,
                              void* d_out, int out_size, void* d_ws, size_t ws_size,
                              hipStream_t stream) {
  const float* x = (const float*)d_in[0];
  const float* qkv_w = (const float*)d_in[1];
  const float* proj_w = (const float*)d_in[2];
  const float* proj_b = (const float*)d_in[3];
  const float* pi_q = (const float*)d_in[4];
  const float* pi_k = (const float*)d_in[5];
  float* out = (float*)d_out;

  unsigned short* ws = (unsigned short*)d_ws;
  const size_t S = (size_t)1536 * 197 * 64;  // 19,365,888 elems per tensor
  unsigned short* Q = ws;
  unsigned short* K = ws + S;
  unsigned short* V = ws + 2 * S;
  unsigned short* Xb = ws + 3 * S;   // aliased: Oa reuses this region after qkv
  unsigned short* Oa = Xb;
  unsigned short* Wb = ws + 4 * S;                 // 2304*768 bf16
  unsigned short* Pb = Wb + (size_t)2304 * 768;    // 768*768 bf16

  dim3 blk(256, 1, 1);
  dim3 blk512(512, 1, 1);
  cvt3_kernel<<<dim3(2048, 1, 1), blk, 0, stream>>>(x, Xb, 2420736,
                                                    qkv_w, Wb, 221184,
                                                    proj_w, Pb, 73728);
  qkv_gemm<<<dim3(197, 18, 1), blk, 0, stream>>>(Xb, Wb, Q, K, V);
  attn_kernel<<<dim3(1536, 1, 1), blk512, 0, stream>>>(Q, K, V, pi_q, pi_k, Oa);
  proj_gemm<<<dim3(197, 6, 1), blk, 0, stream>>>(Oa, Pb, proj_b, out);
}